// Round 8
// baseline (676.034 us; speedup 1.0000x reference)
//
#include <hip/hip_runtime.h>

#define NPTS 8192
#define KNNK 16
#define NSLOT 17          // keep 17, fp64-refine drops the worst -> robust 16-set
#define LEAKY 0.1f

typedef short bf16x8 __attribute__((ext_vector_type(8)));
typedef float f32x4  __attribute__((ext_vector_type(4)));

// ---- knn config (wg=512: compiler gives ~104 VGPR, no scratch spills;
//      wg=1024 pinned VGPR=64 and spilled 421 MB -- R5/R6/R7 lesson) ----
#define KTH   512              // threads/block (8 waves)
#define QPB   128              // queries per block -> grid 256
#define CHN   32               // chunks (threads) per query
#define GQ    8                // queries per thread
#define JLEN  (NPTS / CHN)     // 256 candidates per chunk
#define ROWW  64               // per-query row: [0]=thr [1]=cnt [2..63]=surv idx

// ---------------------------------------------------------------------------
// Kernel 1: exact KNN, expanded-form distance + threshold filter.
//   d' = |c|^2 - 2 c.q  (monotonic per query; 3 fma per pair).
//   Phase 1: per (thread,query) branchless min-2 -> 64-value sketch/query.
//   Threshold: rank-17 of sketch (LDS row table, strict (value,col) order).
//   Phase 2: rescan (bit-identical chain), append survivor indices (rare).
//   Phase 3: one thread/query: recompute d, exact top-17 insertion,
//            streaming fp64 refine (no dd[] array).
// ---------------------------------------------------------------------------
__global__ __launch_bounds__(KTH) void knn_kernel(
    const float* __restrict__ pc1, const float* __restrict__ pc2,
    int* __restrict__ knn_out)
{
    __shared__ float2 sxy[NPTS];          // 64 KB
    __shared__ float  sz[NPTS];           // 32 KB
    __shared__ float  sbuf[QPB][ROWW];    // 32 KB (sketch -> thr/cnt/survivors)

    const int t   = threadIdx.x;
    const int q0  = blockIdx.x * QPB;
    const int dir = q0 >> 14;
    const int b   = (q0 >> 13) & 1;

    const float* __restrict__ pq    = dir ? pc2 : pc1;
    const float* __restrict__ pcand = dir ? pc1 : pc2;

    const float* src = pcand + (size_t)b * NPTS * 3;
    for (int i = t; i < NPTS; i += KTH) {
        sxy[i] = make_float2(src[3 * i], src[3 * i + 1]);
        sz[i]  = src[3 * i + 2];
    }
    __syncthreads();

    const int ch = t & (CHN - 1);      // chunk lane 0..31 (half-wave segment)
    const int qg = t >> 5;             // query group 0..15 (8 queries each)
    const int n0 = q0 & (NPTS - 1);

    float qx2[GQ], qy2[GQ], qz2[GQ];
    #pragma unroll
    for (int g = 0; g < GQ; ++g) {
        const float* qp = pq + ((size_t)b * NPTS + n0 + qg * GQ + g) * 3;
        qx2[g] = -2.0f * qp[0]; qy2[g] = -2.0f * qp[1]; qz2[g] = -2.0f * qp[2];
    }

    // ---- phase 1: branchless min-2 per (thread,query) ----------------------
    float m1[GQ], m2[GQ];
    #pragma unroll
    for (int g = 0; g < GQ; ++g) { m1[g] = 3.0e38f; m2[g] = 3.0e38f; }

    #pragma unroll 4
    for (int j = 0; j < JLEN; ++j) {
        const int idx = j * CHN + ch;
        const float2 cxy = sxy[idx];
        const float  cz  = sz[idx];
        const float  cn  = fmaf(cz, cz, fmaf(cxy.y, cxy.y, cxy.x * cxy.x));
        #pragma unroll
        for (int g = 0; g < GQ; ++g) {
            const float d = fmaf(cz, qz2[g],
                            fmaf(cxy.y, qy2[g],
                            fmaf(cxy.x, qx2[g], cn)));
            m2[g] = __builtin_amdgcn_fmed3f(d, m1[g], m2[g]);  // new 2nd-min
            m1[g] = fminf(m1[g], d);
        }
    }

    // ---- sketch -> LDS row (wave-local rows), rank-17 threshold ------------
    #pragma unroll
    for (int g = 0; g < GQ; ++g) {
        const int row = qg * GQ + g;
        *(float2*)&sbuf[row][2 * ch] = make_float2(m1[g], m2[g]);
    }
    __builtin_amdgcn_wave_barrier();   // sketch rows are wave-local

    int rr1[GQ], rr2[GQ];
    #pragma unroll
    for (int g = 0; g < GQ; ++g) {
        const int row = qg * GQ + g;
        const float v1 = m1[g], v2 = m2[g];
        int r1 = 0, r2 = 0;
        #pragma unroll
        for (int jj = 0; jj < ROWW / 4; ++jj) {
            const float4 sv = *(const float4*)&sbuf[row][4 * jj];
            const float se[4] = {sv.x, sv.y, sv.z, sv.w};
            #pragma unroll
            for (int e = 0; e < 4; ++e) {
                const int col = 4 * jj + e;
                const float vj = se[e];
                r1 += (vj < v1 || (vj == v1 && col < 2 * ch)) ? 1 : 0;
                r2 += (vj < v2 || (vj == v2 && col < 2 * ch + 1)) ? 1 : 0;
            }
        }
        rr1[g] = r1; rr2[g] = r2;
    }
    __builtin_amdgcn_wave_barrier();   // all sketch reads done

    #pragma unroll
    for (int g = 0; g < GQ; ++g) {
        const int row = qg * GQ + g;
        if (rr1[g] == 16) sbuf[row][0] = m1[g];
        if (rr2[g] == 16) sbuf[row][0] = m2[g];
        if (ch == 0) ((int*)&sbuf[row][0])[1] = 2;   // survivor write cursor
    }
    __builtin_amdgcn_wave_barrier();

    float tq[GQ];
    #pragma unroll
    for (int g = 0; g < GQ; ++g) tq[g] = sbuf[qg * GQ + g][0];
    __builtin_amdgcn_wave_barrier();

    // ---- phase 2: collect survivor indices (bit-identical arithmetic) ------
    #pragma unroll 4
    for (int j = 0; j < JLEN; ++j) {
        const int idx = j * CHN + ch;
        const float2 cxy = sxy[idx];
        const float  cz  = sz[idx];
        const float  cn  = fmaf(cz, cz, fmaf(cxy.y, cxy.y, cxy.x * cxy.x));
        #pragma unroll
        for (int g = 0; g < GQ; ++g) {
            const float d = fmaf(cz, qz2[g],
                            fmaf(cxy.y, qy2[g],
                            fmaf(cxy.x, qx2[g], cn)));
            if (d <= tq[g]) {
                const int row = qg * GQ + g;
                const int pos = atomicAdd((int*)&sbuf[row][1], 1);
                if (pos < ROWW) ((int*)&sbuf[row][0])[pos] = idx;
            }
        }
    }
    __syncthreads();

    // ---- phase 3: exact top-17 of survivors + streaming fp64 refine --------
    if (t < QPB) {
        const int* rowp = (const int*)&sbuf[t][0];
        const int nc = min(rowp[1], ROWW) - 2;

        const float* qpp = pq + ((size_t)b * NPTS + n0 + t) * 3;
        const float fqx2 = -2.0f * qpp[0];
        const float fqy2 = -2.0f * qpp[1];
        const float fqz2 = -2.0f * qpp[2];

        float dist[NSLOT];   // sorted descending by (d, idx); dist[0] = worst
        int   ind[NSLOT];
        #pragma unroll
        for (int i = 0; i < NSLOT; ++i) { dist[i] = 3.0e38f; ind[i] = 0x7fffffff; }

        for (int s = 0; s < nc; ++s) {
            const int id = rowp[2 + s];
            const float2 cxy = sxy[id];
            const float  cz  = sz[id];
            const float  cn  = fmaf(cz, cz, fmaf(cxy.y, cxy.y, cxy.x * cxy.x));
            const float d = fmaf(cz, fqz2,
                            fmaf(cxy.y, fqy2,
                            fmaf(cxy.x, fqx2, cn)));
            const bool better0 = (d < dist[0]) || (d == dist[0] && id < ind[0]);
            if (better0) {
                bool cprev = true;
                #pragma unroll
                for (int i = 0; i < NSLOT - 1; ++i) {
                    const bool ci = (d < dist[i + 1]) ||
                                    (d == dist[i + 1] && id < ind[i + 1]);
                    const float nv = ci ? dist[i + 1] : (cprev ? d  : dist[i]);
                    const int   ni = ci ? ind[i + 1]  : (cprev ? id : ind[i]);
                    dist[i] = nv; ind[i] = ni;
                    cprev = ci;
                }
                if (cprev) { dist[NSLOT - 1] = d; ind[NSLOT - 1] = id; }
            }
        }

        // streaming fp64 refine: find worst-of-17 without a dd[] array
        const double dqx = (double)qpp[0], dqy = (double)qpp[1], dqz = (double)qpp[2];
        int worst = 0; double wd = -1.0;
        #pragma unroll 1
        for (int i = 0; i < NSLOT; ++i) {
            const int id = ind[i];
            const float2 cxy = sxy[id];
            const double dx = (double)cxy.x - dqx;
            const double dy = (double)cxy.y - dqy;
            const double dz = (double)sz[id] - dqz;
            const double ddv = dx * dx + dy * dy + dz * dz;
            if (ddv > wd) { wd = ddv; worst = i; }
        }

        int* outp = knn_out + (size_t)(q0 + t) * KNNK;
        int slot = 0;
        #pragma unroll 1
        for (int i = 0; i < NSLOT; ++i) {
            if (i != worst) outp[slot++] = ind[i];
        }
    }
}

// ---------------------------------------------------------------------------
// Kernel 2: feature MLP via bf16x3-split MFMA (unchanged from R4).
// ---------------------------------------------------------------------------
#define FP 4

__device__ __forceinline__ unsigned int packhl(float f) {
    const unsigned int u = __float_as_uint(f);
    const unsigned int h = u & 0xffff0000u;
    const float lf = f - __uint_as_float(h);
    return h | (__float_as_uint(lf) >> 16);
}

__device__ __forceinline__ void build_b(const float* __restrict__ wrow,
                                        bf16x8* hi, bf16x8* lo) {
    union { unsigned int u[4]; bf16x8 v; } H, L;
    #pragma unroll
    for (int r = 0; r < 4; ++r) {
        const float f0 = wrow[2 * r], f1 = wrow[2 * r + 1];
        const unsigned int h0 = __float_as_uint(f0) & 0xffff0000u;
        const unsigned int h1 = __float_as_uint(f1) & 0xffff0000u;
        const float l0 = f0 - __uint_as_float(h0);
        const float l1 = f1 - __uint_as_float(h1);
        H.u[r] = h1 | (h0 >> 16);
        L.u[r] = (__float_as_uint(l1) & 0xffff0000u) | (__float_as_uint(l0) >> 16);
    }
    *hi = H.v; *lo = L.v;
}

__device__ __forceinline__ void unpack_a(const unsigned int* __restrict__ Tu,
                                         bf16x8* hi, bf16x8* lo) {
    union { unsigned int u[4]; bf16x8 v; } H, L;
    #pragma unroll
    for (int r = 0; r < 4; ++r) {
        const unsigned int a = Tu[2 * r + 1], bb = Tu[2 * r];
        H.u[r] = __builtin_amdgcn_perm(a, bb, 0x07060302u);  // [a.hi16 : b.hi16]
        L.u[r] = __builtin_amdgcn_perm(a, bb, 0x05040100u);  // [a.lo16 : b.lo16]
    }
    *hi = H.v; *lo = L.v;
}

__device__ __forceinline__ f32x4 mfma3(f32x4 acc, bf16x8 ah, bf16x8 al,
                                       bf16x8 bh, bf16x8 bl) {
    acc = __builtin_amdgcn_mfma_f32_16x16x32_bf16(ah, bl, acc, 0, 0, 0);
    acc = __builtin_amdgcn_mfma_f32_16x16x32_bf16(al, bh, acc, 0, 0, 0);
    acc = __builtin_amdgcn_mfma_f32_16x16x32_bf16(ah, bh, acc, 0, 0, 0);
    return acc;
}

__global__ __launch_bounds__(256, 4) void feat_kernel(
    const float* __restrict__ pc1, const float* __restrict__ pc2,
    const float* __restrict__ feat1, const float* __restrict__ feat2,
    const float* __restrict__ pos_w, const float* __restrict__ pos_b,
    const float* __restrict__ w0, const float* __restrict__ b0,
    const float* __restrict__ w1, const float* __restrict__ b1,
    const float* __restrict__ t1w, const float* __restrict__ t1b,
    const float* __restrict__ t2w, const float* __restrict__ t2b,
    const int* __restrict__ knn, float* __restrict__ out)
{
    __shared__ unsigned int T0[FP][16][68];   // 17.4 KB packed activations
    __shared__ unsigned int T1[FP][16][68];   // 17.4 KB
    __shared__ float sm[FP][64];              // 1 KB pooled features

    const int t    = threadIdx.x;
    const int w    = t >> 6;          // wave = N-tile index 0..3
    const int lane = t & 63;
    const int m    = lane & 15;       // A-row (neighbor) / C-col (channel)
    const int quad = lane >> 4;

    const int p0  = blockIdx.x * FP;
    const int dir = p0 >> 14, bt = (p0 >> 13) & 1;
    const int n0  = p0 & (NPTS - 1);

    const float* __restrict__ pqd = dir ? pc2 : pc1;
    const float* __restrict__ pcd = dir ? pc1 : pc2;
    const float* __restrict__ fqd = dir ? feat2 : feat1;
    const float* __restrict__ fcd = dir ? feat1 : feat2;

    // ---- register-resident B-fragments: B[k][n] = W[n_glob][k] -------------
    const int ocol = w * 16 + m;               // this lane's output channel
    bf16x8 Bh[2][2], Bl[2][2];                 // [layer][ktile]
    #pragma unroll
    for (int kt = 0; kt < 2; ++kt) {
        build_b(&w0[(size_t)ocol * 64 + kt * 32 + quad * 8], &Bh[0][kt], &Bl[0][kt]);
        build_b(&w1[(size_t)ocol * 64 + kt * 32 + quad * 8], &Bh[1][kt], &Bl[1][kt]);
    }
    const float bias1 = b0[ocol];
    const float bias2 = b1[ocol];

    // ---- init-stage per-lane constants: channels cg0..cg0+3 ----------------
    const int cg0 = w * 16 + quad * 4;
    float pbc[4], pwx[4], pwy[4], pwz[4];
    #pragma unroll
    for (int i = 0; i < 4; ++i) {
        pbc[i] = pos_b[cg0 + i];
        pwx[i] = pos_w[(cg0 + i) * 3 + 0];
        pwy[i] = pos_w[(cg0 + i) * 3 + 1];
        pwz[i] = pos_w[(cg0 + i) * 3 + 2];
    }

    // ---- stage A: initial layer -> T0 (packed) -----------------------------
    #pragma unroll
    for (int pt = 0; pt < FP; ++pt) {
        const int p = p0 + pt, n = n0 + pt;
        const int id = knn[(size_t)p * KNNK + m];
        const float* qp  = pqd + ((size_t)bt * NPTS + n) * 3;
        const float* nbp = pcd + ((size_t)bt * NPTS + id) * 3;
        const float dx = nbp[0] - qp[0];
        const float dy = nbp[1] - qp[1];
        const float dz = nbp[2] - qp[2];
        const float4 gf = *(const float4*)&fcd[((size_t)bt * NPTS + id) * 64 + cg0];
        const float4 fq = *(const float4*)&fqd[((size_t)bt * NPTS + n) * 64 + cg0];
        const float gfa[4] = {gf.x, gf.y, gf.z, gf.w};
        const float fqa[4] = {fq.x, fq.y, fq.z, fq.w};
        uint4 U;
        unsigned int* Up = (unsigned int*)&U;
        #pragma unroll
        for (int i = 0; i < 4; ++i) {
            float v = gfa[i] + fqa[i] + pbc[i];
            v = fmaf(dx, pwx[i], v);
            v = fmaf(dy, pwy[i], v);
            v = fmaf(dz, pwz[i], v);
            v = fmaxf(v, LEAKY * v);
            Up[i] = packhl(v);
        }
        *(uint4*)&T0[pt][m][cg0] = U;
    }
    __syncthreads();

    // ---- stage B: layer 1 (MFMA) -> T1 -------------------------------------
    #pragma unroll
    for (int pt = 0; pt < FP; ++pt) {
        unsigned int Tu[8];
        bf16x8 Ah, Al;
        f32x4 acc = {0.f, 0.f, 0.f, 0.f};
        #pragma unroll
        for (int kt = 0; kt < 2; ++kt) {
            *(uint4*)&Tu[0] = *(const uint4*)&T0[pt][m][kt * 32 + quad * 8];
            *(uint4*)&Tu[4] = *(const uint4*)&T0[pt][m][kt * 32 + quad * 8 + 4];
            unpack_a(Tu, &Ah, &Al);
            acc = mfma3(acc, Ah, Al, Bh[0][kt], Bl[0][kt]);
        }
        #pragma unroll
        for (int r = 0; r < 4; ++r) {
            float v = acc[r] + bias1;
            v = fmaxf(v, LEAKY * v);
            T1[pt][quad * 4 + r][ocol] = packhl(v);
        }
    }
    __syncthreads();

    // ---- stage C: layer 2 (MFMA) + max-pool -> sm --------------------------
    #pragma unroll
    for (int pt = 0; pt < FP; ++pt) {
        unsigned int Tu[8];
        bf16x8 Ah, Al;
        f32x4 acc = {0.f, 0.f, 0.f, 0.f};
        #pragma unroll
        for (int kt = 0; kt < 2; ++kt) {
            *(uint4*)&Tu[0] = *(const uint4*)&T1[pt][m][kt * 32 + quad * 8];
            *(uint4*)&Tu[4] = *(const uint4*)&T1[pt][m][kt * 32 + quad * 8 + 4];
            unpack_a(Tu, &Ah, &Al);
            acc = mfma3(acc, Ah, Al, Bh[1][kt], Bl[1][kt]);
        }
        float mx = -3.0e38f;
        #pragma unroll
        for (int r = 0; r < 4; ++r) {
            float v = acc[r] + bias2;
            v = fmaxf(v, LEAKY * v);
            mx = fmaxf(mx, v);
        }
        mx = fmaxf(mx, __shfl_xor(mx, 16));
        mx = fmaxf(mx, __shfl_xor(mx, 32));
        if (quad == 0) sm[pt][ocol] = mx;
    }
    __syncthreads();

    // ---- stage D: final 64->128 linear -------------------------------------
    {
        const float* __restrict__ tw = dir ? t2w : t1w;
        const float* __restrict__ tb = dir ? t2b : t1b;
        const int o  = t & 127;
        const int pg = t >> 7;                 // 2 point-pairs
        const int pa = pg * 2, pb = pg * 2 + 1;
        float acc0 = tb[o], acc1 = acc0;
        #pragma unroll
        for (int cc = 0; cc < 64; cc += 4) {
            const float4 wq = *(const float4*)&tw[(size_t)o * 64 + cc];
            const float4 a0 = *(const float4*)&sm[pa][cc];
            const float4 a1 = *(const float4*)&sm[pb][cc];
            acc0 = fmaf(a0.x, wq.x, acc0); acc0 = fmaf(a0.y, wq.y, acc0);
            acc0 = fmaf(a0.z, wq.z, acc0); acc0 = fmaf(a0.w, wq.w, acc0);
            acc1 = fmaf(a1.x, wq.x, acc1); acc1 = fmaf(a1.y, wq.y, acc1);
            acc1 = fmaf(a1.z, wq.z, acc1); acc1 = fmaf(a1.w, wq.w, acc1);
        }
        float* op = out + (size_t)dir * (2 * NPTS * 128);
        op[((size_t)bt * NPTS + n0 + pa) * 128 + o] = acc0;
        op[((size_t)bt * NPTS + n0 + pb) * 128 + o] = acc1;
    }
}

// ---------------------------------------------------------------------------
extern "C" void kernel_launch(void* const* d_in, const int* in_sizes, int n_in,
                              void* d_out, int out_size, void* d_ws, size_t ws_size,
                              hipStream_t stream)
{
    const float* pc1   = (const float*)d_in[0];
    const float* pc2   = (const float*)d_in[1];
    const float* feat1 = (const float*)d_in[2];
    const float* feat2 = (const float*)d_in[3];
    const float* pos_w = (const float*)d_in[4];
    const float* pos_b = (const float*)d_in[5];
    const float* w0    = (const float*)d_in[6];
    const float* b0    = (const float*)d_in[7];
    const float* w1    = (const float*)d_in[8];
    const float* b1    = (const float*)d_in[9];
    const float* t1w   = (const float*)d_in[10];
    const float* t1b   = (const float*)d_in[11];
    const float* t2w   = (const float*)d_in[12];
    const float* t2b   = (const float*)d_in[13];

    int*   knn = (int*)d_ws;          // 32768 * 16 ints = 2 MB scratch
    float* out = (float*)d_out;

    hipLaunchKernelGGL(knn_kernel, dim3(32768 / QPB), dim3(KTH), 0, stream,
                       pc1, pc2, knn);
    hipLaunchKernelGGL(feat_kernel, dim3(32768 / FP), dim3(256), 0, stream,
                       pc1, pc2, feat1, feat2, pos_w, pos_b,
                       w0, b0, w1, b1, t1w, t1b, t2w, t2b, knn, out);
}

// Round 9
// 413.576 us; speedup vs baseline: 1.6346x; 1.6346x over previous
//
#include <hip/hip_runtime.h>

#define NPTS 8192
#define KNNK 16
#define NSLOT 17          // keep 17, fp64-refine drops the worst -> robust 16-set
#define LEAKY 0.1f

typedef short bf16x8 __attribute__((ext_vector_type(8)));
typedef float f32x4  __attribute__((ext_vector_type(4)));

// ---- knn config (R4-proven: VGPR=104, FETCH/WRITE ~2 MB, 222 us) ----
#define KTH   512              // threads/block (8 waves)
#define QPB   128              // queries per block -> grid 256
#define CHN   32               // chunks (threads) per query
#define GQ    8                // queries per thread
#define JLEN  (NPTS / CHN)     // 256 candidates per chunk
#define BUFCAP 48              // survivor buffer per query

// ---------------------------------------------------------------------------
// Kernel 1: exact KNN, query-register-blocked threshold filter.
// VERBATIM R4 kernel. R5-R8 variants (float2 layout / consolidated sbuf /
// expanded distance) all carried an unexplained ~648 MB HBM traffic
// signature; this shape is the proven-clean one. Do not modify piecemeal.
// ---------------------------------------------------------------------------
__global__ __launch_bounds__(KTH) void knn_kernel(
    const float* __restrict__ pc1, const float* __restrict__ pc2,
    int* __restrict__ knn_out)
{
    __shared__ float sx[NPTS], sy[NPTS], sz[NPTS];   // 96 KB candidate SoA
    // per-query row of 96 floats: [0..47] survd, [48..95] survi (as int).
    // cols [0..63] double as the rank table before phase 2 (wave-local).
    __shared__ float sbuf[QPB][2 * BUFCAP];          // 48 KB
    __shared__ float sthr[QPB];
    __shared__ int   scnt[QPB];

    const int t   = threadIdx.x;
    const int q0  = blockIdx.x * QPB;
    const int dir = q0 >> 14;
    const int b   = (q0 >> 13) & 1;

    const float* __restrict__ pq    = dir ? pc2 : pc1;
    const float* __restrict__ pcand = dir ? pc1 : pc2;

    const float* src = pcand + (size_t)b * NPTS * 3;
    for (int i = t; i < NPTS; i += KTH) {
        sx[i] = src[3 * i];
        sy[i] = src[3 * i + 1];
        sz[i] = src[3 * i + 2];
    }
    if (t < QPB) scnt[t] = 0;
    __syncthreads();

    const int ch = t & (CHN - 1);      // chunk 0..31
    const int qg = t >> 5;             // query group 0..15 (8 queries each)
    const int n0 = q0 & (NPTS - 1);

    float qx[GQ], qy[GQ], qz[GQ];
    #pragma unroll
    for (int g = 0; g < GQ; ++g) {
        const float* qp = pq + ((size_t)b * NPTS + n0 + qg * GQ + g) * 3;
        qx[g] = qp[0]; qy[g] = qp[1]; qz[g] = qp[2];
    }

    // ---- phase 1: min-2 per (thread,query), branchless ---------------------
    float m1[GQ], m2[GQ];
    #pragma unroll
    for (int g = 0; g < GQ; ++g) { m1[g] = 3.0e38f; m2[g] = 3.0e38f; }

    #pragma unroll 4
    for (int j = 0; j < JLEN; ++j) {
        const int idx = j * CHN + ch;
        const float cx = sx[idx], cy = sy[idx], cz = sz[idx];
        #pragma unroll
        for (int g = 0; g < GQ; ++g) {
            const float dx = cx - qx[g];
            const float dy = cy - qy[g];
            const float dz = cz - qz[g];
            const float d  = fmaf(dx, dx, fmaf(dy, dy, dz * dz));
            m2[g] = fminf(m2[g], fmaxf(m1[g], d));   // median3 keeps 2nd-min
            m1[g] = fminf(m1[g], d);
        }
    }

    // ---- threshold: rank-16 (0-based) of 64 collected, LDS rank table ------
    #pragma unroll
    for (int g = 0; g < GQ; ++g) {
        const int row = qg * GQ + g;
        sbuf[row][2 * ch]     = m1[g];
        sbuf[row][2 * ch + 1] = m2[g];
    }
    __builtin_amdgcn_wave_barrier();   // table rows are wave-local

    #pragma unroll
    for (int g = 0; g < GQ; ++g) {
        const int row = qg * GQ + g;
        const float v1 = m1[g], v2 = m2[g];
        int r1 = 0, r2 = 0;
        #pragma unroll
        for (int jj = 0; jj < 2 * CHN; ++jj) {
            const float vj = sbuf[row][jj];
            r1 += (vj < v1 || (vj == v1 && jj < 2 * ch)) ? 1 : 0;
            r2 += (vj < v2 || (vj == v2 && jj < 2 * ch + 1)) ? 1 : 0;
        }
        if (r1 == 16) sthr[row] = v1;
        if (r2 == 16) sthr[row] = v2;
    }
    __builtin_amdgcn_wave_barrier();

    // ---- phase 2: collect survivors (identical fp32 arithmetic) ------------
    float tq[GQ];
    #pragma unroll
    for (int g = 0; g < GQ; ++g) tq[g] = sthr[qg * GQ + g];

    #pragma unroll 4
    for (int j = 0; j < JLEN; ++j) {
        const int idx = j * CHN + ch;
        const float cx = sx[idx], cy = sy[idx], cz = sz[idx];
        #pragma unroll
        for (int g = 0; g < GQ; ++g) {
            const float dx = cx - qx[g];
            const float dy = cy - qy[g];
            const float dz = cz - qz[g];
            const float d  = fmaf(dx, dx, fmaf(dy, dy, dz * dz));
            if (d <= tq[g]) {
                const int q = qg * GQ + g;
                const int pos = atomicAdd(&scnt[q], 1);
                if (pos < BUFCAP) {
                    sbuf[q][pos] = d;
                    ((int*)&sbuf[q][BUFCAP])[pos] = idx;
                }
            }
        }
    }
    __syncthreads();

    // ---- phase 3: exact top-17 of survivors + fp64 refine ------------------
    if (t < QPB) {
        const int nc = min(scnt[t], BUFCAP);

        float dist[NSLOT];   // sorted descending by (d, idx); dist[0] = worst
        int   ind[NSLOT];
        #pragma unroll
        for (int i = 0; i < NSLOT; ++i) { dist[i] = 3.0e38f; ind[i] = 0x7fffffff; }

        for (int s = 0; s < nc; ++s) {
            const float d  = sbuf[t][s];
            const int   id = ((int*)&sbuf[t][BUFCAP])[s];
            const bool better0 = (d < dist[0]) || (d == dist[0] && id < ind[0]);
            if (better0) {
                bool cprev = true;
                #pragma unroll
                for (int i = 0; i < NSLOT - 1; ++i) {
                    const bool ci = (d < dist[i + 1]) ||
                                    (d == dist[i + 1] && id < ind[i + 1]);
                    const float nv = ci ? dist[i + 1] : (cprev ? d  : dist[i]);
                    const int   ni = ci ? ind[i + 1]  : (cprev ? id : ind[i]);
                    dist[i] = nv; ind[i] = ni;
                    cprev = ci;
                }
                if (cprev) { dist[NSLOT - 1] = d; ind[NSLOT - 1] = id; }
            }
        }

        const float* qpp = pq + ((size_t)b * NPTS + n0 + t) * 3;
        const double dqx = (double)qpp[0], dqy = (double)qpp[1], dqz = (double)qpp[2];
        double dd[NSLOT];
        #pragma unroll
        for (int i = 0; i < NSLOT; ++i) {
            const int id = ind[i];
            const double dx = (double)sx[id] - dqx;
            const double dy = (double)sy[id] - dqy;
            const double dz = (double)sz[id] - dqz;
            dd[i] = dx * dx + dy * dy + dz * dz;
        }
        int worst = 0; double wd = dd[0];
        #pragma unroll
        for (int i = 1; i < NSLOT; ++i) { if (dd[i] > wd) { wd = dd[i]; worst = i; } }

        int* outp = knn_out + (size_t)(q0 + t) * KNNK;
        int slot = 0;
        #pragma unroll
        for (int i = 0; i < NSLOT; ++i) {
            if (i != worst) outp[slot++] = ind[i];
        }
    }
}

// ---------------------------------------------------------------------------
// Kernel 2: feature MLP via bf16x3-split MFMA (R4 + knn-index prefetch:
// the 4 neighbor-index loads head stage A's dependent chain; issuing them
// at kernel entry overlaps their latency with the weight-fragment build).
// ---------------------------------------------------------------------------
#define FP 4

__device__ __forceinline__ unsigned int packhl(float f) {
    const unsigned int u = __float_as_uint(f);
    const unsigned int h = u & 0xffff0000u;
    const float lf = f - __uint_as_float(h);
    return h | (__float_as_uint(lf) >> 16);
}

__device__ __forceinline__ void build_b(const float* __restrict__ wrow,
                                        bf16x8* hi, bf16x8* lo) {
    union { unsigned int u[4]; bf16x8 v; } H, L;
    #pragma unroll
    for (int r = 0; r < 4; ++r) {
        const float f0 = wrow[2 * r], f1 = wrow[2 * r + 1];
        const unsigned int h0 = __float_as_uint(f0) & 0xffff0000u;
        const unsigned int h1 = __float_as_uint(f1) & 0xffff0000u;
        const float l0 = f0 - __uint_as_float(h0);
        const float l1 = f1 - __uint_as_float(h1);
        H.u[r] = h1 | (h0 >> 16);
        L.u[r] = (__float_as_uint(l1) & 0xffff0000u) | (__float_as_uint(l0) >> 16);
    }
    *hi = H.v; *lo = L.v;
}

__device__ __forceinline__ void unpack_a(const unsigned int* __restrict__ Tu,
                                         bf16x8* hi, bf16x8* lo) {
    union { unsigned int u[4]; bf16x8 v; } H, L;
    #pragma unroll
    for (int r = 0; r < 4; ++r) {
        const unsigned int a = Tu[2 * r + 1], bb = Tu[2 * r];
        H.u[r] = __builtin_amdgcn_perm(a, bb, 0x07060302u);  // [a.hi16 : b.hi16]
        L.u[r] = __builtin_amdgcn_perm(a, bb, 0x05040100u);  // [a.lo16 : b.lo16]
    }
    *hi = H.v; *lo = L.v;
}

__device__ __forceinline__ f32x4 mfma3(f32x4 acc, bf16x8 ah, bf16x8 al,
                                       bf16x8 bh, bf16x8 bl) {
    acc = __builtin_amdgcn_mfma_f32_16x16x32_bf16(ah, bl, acc, 0, 0, 0);
    acc = __builtin_amdgcn_mfma_f32_16x16x32_bf16(al, bh, acc, 0, 0, 0);
    acc = __builtin_amdgcn_mfma_f32_16x16x32_bf16(ah, bh, acc, 0, 0, 0);
    return acc;
}

__global__ __launch_bounds__(256, 4) void feat_kernel(
    const float* __restrict__ pc1, const float* __restrict__ pc2,
    const float* __restrict__ feat1, const float* __restrict__ feat2,
    const float* __restrict__ pos_w, const float* __restrict__ pos_b,
    const float* __restrict__ w0, const float* __restrict__ b0,
    const float* __restrict__ w1, const float* __restrict__ b1,
    const float* __restrict__ t1w, const float* __restrict__ t1b,
    const float* __restrict__ t2w, const float* __restrict__ t2b,
    const int* __restrict__ knn, float* __restrict__ out)
{
    __shared__ unsigned int T0[FP][16][68];   // 17.4 KB packed activations
    __shared__ unsigned int T1[FP][16][68];   // 17.4 KB
    __shared__ float sm[FP][64];              // 1 KB pooled features

    const int t    = threadIdx.x;
    const int w    = t >> 6;          // wave = N-tile index 0..3
    const int lane = t & 63;
    const int m    = lane & 15;       // A-row (neighbor) / C-col (channel)
    const int quad = lane >> 4;

    const int p0  = blockIdx.x * FP;
    const int dir = p0 >> 14, bt = (p0 >> 13) & 1;
    const int n0  = p0 & (NPTS - 1);

    const float* __restrict__ pqd = dir ? pc2 : pc1;
    const float* __restrict__ pcd = dir ? pc1 : pc2;
    const float* __restrict__ fqd = dir ? feat2 : feat1;
    const float* __restrict__ fcd = dir ? feat1 : feat2;

    // ---- prefetch neighbor ids: head of stage A's dependent-load chain -----
    int ids[FP];
    #pragma unroll
    for (int pt = 0; pt < FP; ++pt)
        ids[pt] = knn[(size_t)(p0 + pt) * KNNK + m];

    // ---- register-resident B-fragments: B[k][n] = W[n_glob][k] -------------
    const int ocol = w * 16 + m;               // this lane's output channel
    bf16x8 Bh[2][2], Bl[2][2];                 // [layer][ktile]
    #pragma unroll
    for (int kt = 0; kt < 2; ++kt) {
        build_b(&w0[(size_t)ocol * 64 + kt * 32 + quad * 8], &Bh[0][kt], &Bl[0][kt]);
        build_b(&w1[(size_t)ocol * 64 + kt * 32 + quad * 8], &Bh[1][kt], &Bl[1][kt]);
    }
    const float bias1 = b0[ocol];
    const float bias2 = b1[ocol];

    // ---- init-stage per-lane constants: channels cg0..cg0+3 ----------------
    const int cg0 = w * 16 + quad * 4;
    float pbc[4], pwx[4], pwy[4], pwz[4];
    #pragma unroll
    for (int i = 0; i < 4; ++i) {
        pbc[i] = pos_b[cg0 + i];
        pwx[i] = pos_w[(cg0 + i) * 3 + 0];
        pwy[i] = pos_w[(cg0 + i) * 3 + 1];
        pwz[i] = pos_w[(cg0 + i) * 3 + 2];
    }

    // ---- stage A: initial layer -> T0 (packed) -----------------------------
    #pragma unroll
    for (int pt = 0; pt < FP; ++pt) {
        const int n = n0 + pt;
        const int id = ids[pt];
        const float* qp  = pqd + ((size_t)bt * NPTS + n) * 3;
        const float* nbp = pcd + ((size_t)bt * NPTS + id) * 3;
        const float dx = nbp[0] - qp[0];
        const float dy = nbp[1] - qp[1];
        const float dz = nbp[2] - qp[2];
        const float4 gf = *(const float4*)&fcd[((size_t)bt * NPTS + id) * 64 + cg0];
        const float4 fq = *(const float4*)&fqd[((size_t)bt * NPTS + n) * 64 + cg0];
        const float gfa[4] = {gf.x, gf.y, gf.z, gf.w};
        const float fqa[4] = {fq.x, fq.y, fq.z, fq.w};
        uint4 U;
        unsigned int* Up = (unsigned int*)&U;
        #pragma unroll
        for (int i = 0; i < 4; ++i) {
            float v = gfa[i] + fqa[i] + pbc[i];
            v = fmaf(dx, pwx[i], v);
            v = fmaf(dy, pwy[i], v);
            v = fmaf(dz, pwz[i], v);
            v = fmaxf(v, LEAKY * v);
            Up[i] = packhl(v);
        }
        *(uint4*)&T0[pt][m][cg0] = U;
    }
    __syncthreads();

    // ---- stage B: layer 1 (MFMA) -> T1 -------------------------------------
    #pragma unroll
    for (int pt = 0; pt < FP; ++pt) {
        unsigned int Tu[8];
        bf16x8 Ah, Al;
        f32x4 acc = {0.f, 0.f, 0.f, 0.f};
        #pragma unroll
        for (int kt = 0; kt < 2; ++kt) {
            *(uint4*)&Tu[0] = *(const uint4*)&T0[pt][m][kt * 32 + quad * 8];
            *(uint4*)&Tu[4] = *(const uint4*)&T0[pt][m][kt * 32 + quad * 8 + 4];
            unpack_a(Tu, &Ah, &Al);
            acc = mfma3(acc, Ah, Al, Bh[0][kt], Bl[0][kt]);
        }
        #pragma unroll
        for (int r = 0; r < 4; ++r) {
            float v = acc[r] + bias1;
            v = fmaxf(v, LEAKY * v);
            T1[pt][quad * 4 + r][ocol] = packhl(v);
        }
    }
    __syncthreads();

    // ---- stage C: layer 2 (MFMA) + max-pool -> sm --------------------------
    #pragma unroll
    for (int pt = 0; pt < FP; ++pt) {
        unsigned int Tu[8];
        bf16x8 Ah, Al;
        f32x4 acc = {0.f, 0.f, 0.f, 0.f};
        #pragma unroll
        for (int kt = 0; kt < 2; ++kt) {
            *(uint4*)&Tu[0] = *(const uint4*)&T1[pt][m][kt * 32 + quad * 8];
            *(uint4*)&Tu[4] = *(const uint4*)&T1[pt][m][kt * 32 + quad * 8 + 4];
            unpack_a(Tu, &Ah, &Al);
            acc = mfma3(acc, Ah, Al, Bh[1][kt], Bl[1][kt]);
        }
        float mx = -3.0e38f;
        #pragma unroll
        for (int r = 0; r < 4; ++r) {
            float v = acc[r] + bias2;
            v = fmaxf(v, LEAKY * v);
            mx = fmaxf(mx, v);
        }
        mx = fmaxf(mx, __shfl_xor(mx, 16));
        mx = fmaxf(mx, __shfl_xor(mx, 32));
        if (quad == 0) sm[pt][ocol] = mx;
    }
    __syncthreads();

    // ---- stage D: final 64->128 linear -------------------------------------
    {
        const float* __restrict__ tw = dir ? t2w : t1w;
        const float* __restrict__ tb = dir ? t2b : t1b;
        const int o  = t & 127;
        const int pg = t >> 7;                 // 2 point-pairs
        const int pa = pg * 2, pb = pg * 2 + 1;
        float acc0 = tb[o], acc1 = acc0;
        #pragma unroll
        for (int cc = 0; cc < 64; cc += 4) {
            const float4 wq = *(const float4*)&tw[(size_t)o * 64 + cc];
            const float4 a0 = *(const float4*)&sm[pa][cc];
            const float4 a1 = *(const float4*)&sm[pb][cc];
            acc0 = fmaf(a0.x, wq.x, acc0); acc0 = fmaf(a0.y, wq.y, acc0);
            acc0 = fmaf(a0.z, wq.z, acc0); acc0 = fmaf(a0.w, wq.w, acc0);
            acc1 = fmaf(a1.x, wq.x, acc1); acc1 = fmaf(a1.y, wq.y, acc1);
            acc1 = fmaf(a1.z, wq.z, acc1); acc1 = fmaf(a1.w, wq.w, acc1);
        }
        float* op = out + (size_t)dir * (2 * NPTS * 128);
        op[((size_t)bt * NPTS + n0 + pa) * 128 + o] = acc0;
        op[((size_t)bt * NPTS + n0 + pb) * 128 + o] = acc1;
    }
}

// ---------------------------------------------------------------------------
extern "C" void kernel_launch(void* const* d_in, const int* in_sizes, int n_in,
                              void* d_out, int out_size, void* d_ws, size_t ws_size,
                              hipStream_t stream)
{
    const float* pc1   = (const float*)d_in[0];
    const float* pc2   = (const float*)d_in[1];
    const float* feat1 = (const float*)d_in[2];
    const float* feat2 = (const float*)d_in[3];
    const float* pos_w = (const float*)d_in[4];
    const float* pos_b = (const float*)d_in[5];
    const float* w0    = (const float*)d_in[6];
    const float* b0    = (const float*)d_in[7];
    const float* w1    = (const float*)d_in[8];
    const float* b1    = (const float*)d_in[9];
    const float* t1w   = (const float*)d_in[10];
    const float* t1b   = (const float*)d_in[11];
    const float* t2w   = (const float*)d_in[12];
    const float* t2b   = (const float*)d_in[13];

    int*   knn = (int*)d_ws;          // 32768 * 16 ints = 2 MB scratch
    float* out = (float*)d_out;

    hipLaunchKernelGGL(knn_kernel, dim3(32768 / QPB), dim3(KTH), 0, stream,
                       pc1, pc2, knn);
    hipLaunchKernelGGL(feat_kernel, dim3(32768 / FP), dim3(256), 0, stream,
                       pc1, pc2, feat1, feat2, pos_w, pos_b,
                       w0, b0, w1, b1, t1w, t1b, t2w, t2b, knn, out);
}